// Round 9
// baseline (135.467 us; speedup 1.0000x reference)
//
#include <hip/hip_runtime.h>
#include <math.h>

#define NB 7
#define EPS_ 0.02f
#define ITERS_ 200
#define TINY_ 1e-40f
#define LOG2E_ 1.4426950408889634f
#define LN2_   0.6931471805599453f

// Bare hardware transcendentals (base-2 domain).
__device__ __forceinline__ float exp2_hw(float x) {
#if __has_builtin(__builtin_amdgcn_exp2f)
    return __builtin_amdgcn_exp2f(x);
#else
    return __expf(x * LN2_);
#endif
}
__device__ __forceinline__ float log2_hw(float x) {
#if __has_builtin(__builtin_amdgcn_logf)
    return __builtin_amdgcn_logf(x);
#else
    return __logf(x) * LOG2E_;
#endif
}

// ---- DPP helpers (prologue/epilogue only) ----
template <int CTRL>
__device__ __forceinline__ float dpp_ident(float identity, float x) {
    return __int_as_float(__builtin_amdgcn_update_dpp(
        __float_as_int(identity), __float_as_int(x), CTRL, 0xF, 0xF, false));
}
__device__ __forceinline__ float readlane63(float x) {
    return __int_as_float(__builtin_amdgcn_readlane(__float_as_int(x), 63));
}
__device__ __forceinline__ float wave_sum_bcast(float s) {
    s += dpp_ident<0x111>(0.f, s);
    s += dpp_ident<0x112>(0.f, s);
    s += dpp_ident<0x114>(0.f, s);
    s += dpp_ident<0x118>(0.f, s);
    s += dpp_ident<0x142>(0.f, s);
    s += dpp_ident<0x143>(0.f, s);
    return readlane63(s);
}
__device__ __forceinline__ float wave_max_bcast(float m) {
    const float NI = __int_as_float(0xff800000);
    m = fmaxf(m, dpp_ident<0x111>(NI, m));
    m = fmaxf(m, dpp_ident<0x112>(NI, m));
    m = fmaxf(m, dpp_ident<0x114>(NI, m));
    m = fmaxf(m, dpp_ident<0x118>(NI, m));
    m = fmaxf(m, dpp_ident<0x142>(NI, m));
    m = fmaxf(m, dpp_ident<0x143>(NI, m));
    return readlane63(m);
}

// 7-column interleaved 64-lane MAX reduce (keep-old DPP = identity-free).
#define WAVE_MAX7(v0,v1,v2,v3,v4,v5,v6, m0,m1,m2,m3,m4,m5,m6)                 \
  {                                                                           \
    float r0,r1,r2,r3,r4,r5,r6;                                               \
    asm("v_mov_b32 %0, %14\n\t"                                               \
        "v_mov_b32 %1, %15\n\t"                                               \
        "v_mov_b32 %2, %16\n\t"                                               \
        "v_mov_b32 %3, %17\n\t"                                               \
        "v_mov_b32 %4, %18\n\t"                                               \
        "v_mov_b32 %5, %19\n\t"                                               \
        "v_mov_b32 %6, %20\n\t"                                               \
        "v_max_f32_dpp %0, %0, %0 row_shr:1 row_mask:0xf bank_mask:0xf\n\t"   \
        "v_max_f32_dpp %1, %1, %1 row_shr:1 row_mask:0xf bank_mask:0xf\n\t"   \
        "v_max_f32_dpp %2, %2, %2 row_shr:1 row_mask:0xf bank_mask:0xf\n\t"   \
        "v_max_f32_dpp %3, %3, %3 row_shr:1 row_mask:0xf bank_mask:0xf\n\t"   \
        "v_max_f32_dpp %4, %4, %4 row_shr:1 row_mask:0xf bank_mask:0xf\n\t"   \
        "v_max_f32_dpp %5, %5, %5 row_shr:1 row_mask:0xf bank_mask:0xf\n\t"   \
        "v_max_f32_dpp %6, %6, %6 row_shr:1 row_mask:0xf bank_mask:0xf\n\t"   \
        "v_max_f32_dpp %0, %0, %0 row_shr:2 row_mask:0xf bank_mask:0xf\n\t"   \
        "v_max_f32_dpp %1, %1, %1 row_shr:2 row_mask:0xf bank_mask:0xf\n\t"   \
        "v_max_f32_dpp %2, %2, %2 row_shr:2 row_mask:0xf bank_mask:0xf\n\t"   \
        "v_max_f32_dpp %3, %3, %3 row_shr:2 row_mask:0xf bank_mask:0xf\n\t"   \
        "v_max_f32_dpp %4, %4, %4 row_shr:2 row_mask:0xf bank_mask:0xf\n\t"   \
        "v_max_f32_dpp %5, %5, %5 row_shr:2 row_mask:0xf bank_mask:0xf\n\t"   \
        "v_max_f32_dpp %6, %6, %6 row_shr:2 row_mask:0xf bank_mask:0xf\n\t"   \
        "v_max_f32_dpp %0, %0, %0 row_shr:4 row_mask:0xf bank_mask:0xf\n\t"   \
        "v_max_f32_dpp %1, %1, %1 row_shr:4 row_mask:0xf bank_mask:0xf\n\t"   \
        "v_max_f32_dpp %2, %2, %2 row_shr:4 row_mask:0xf bank_mask:0xf\n\t"   \
        "v_max_f32_dpp %3, %3, %3 row_shr:4 row_mask:0xf bank_mask:0xf\n\t"   \
        "v_max_f32_dpp %4, %4, %4 row_shr:4 row_mask:0xf bank_mask:0xf\n\t"   \
        "v_max_f32_dpp %5, %5, %5 row_shr:4 row_mask:0xf bank_mask:0xf\n\t"   \
        "v_max_f32_dpp %6, %6, %6 row_shr:4 row_mask:0xf bank_mask:0xf\n\t"   \
        "v_max_f32_dpp %0, %0, %0 row_shr:8 row_mask:0xf bank_mask:0xf\n\t"   \
        "v_max_f32_dpp %1, %1, %1 row_shr:8 row_mask:0xf bank_mask:0xf\n\t"   \
        "v_max_f32_dpp %2, %2, %2 row_shr:8 row_mask:0xf bank_mask:0xf\n\t"   \
        "v_max_f32_dpp %3, %3, %3 row_shr:8 row_mask:0xf bank_mask:0xf\n\t"   \
        "v_max_f32_dpp %4, %4, %4 row_shr:8 row_mask:0xf bank_mask:0xf\n\t"   \
        "v_max_f32_dpp %5, %5, %5 row_shr:8 row_mask:0xf bank_mask:0xf\n\t"   \
        "v_max_f32_dpp %6, %6, %6 row_shr:8 row_mask:0xf bank_mask:0xf\n\t"   \
        "v_max_f32_dpp %0, %0, %0 row_bcast:15 row_mask:0xa bank_mask:0xf\n\t"\
        "v_max_f32_dpp %1, %1, %1 row_bcast:15 row_mask:0xa bank_mask:0xf\n\t"\
        "v_max_f32_dpp %2, %2, %2 row_bcast:15 row_mask:0xa bank_mask:0xf\n\t"\
        "v_max_f32_dpp %3, %3, %3 row_bcast:15 row_mask:0xa bank_mask:0xf\n\t"\
        "v_max_f32_dpp %4, %4, %4 row_bcast:15 row_mask:0xa bank_mask:0xf\n\t"\
        "v_max_f32_dpp %5, %5, %5 row_bcast:15 row_mask:0xa bank_mask:0xf\n\t"\
        "v_max_f32_dpp %6, %6, %6 row_bcast:15 row_mask:0xa bank_mask:0xf\n\t"\
        "v_max_f32_dpp %0, %0, %0 row_bcast:31 row_mask:0xc bank_mask:0xf\n\t"\
        "v_max_f32_dpp %1, %1, %1 row_bcast:31 row_mask:0xc bank_mask:0xf\n\t"\
        "v_max_f32_dpp %2, %2, %2 row_bcast:31 row_mask:0xc bank_mask:0xf\n\t"\
        "v_max_f32_dpp %3, %3, %3 row_bcast:31 row_mask:0xc bank_mask:0xf\n\t"\
        "v_max_f32_dpp %4, %4, %4 row_bcast:31 row_mask:0xc bank_mask:0xf\n\t"\
        "v_max_f32_dpp %5, %5, %5 row_bcast:31 row_mask:0xc bank_mask:0xf\n\t"\
        "v_max_f32_dpp %6, %6, %6 row_bcast:31 row_mask:0xc bank_mask:0xf\n\t"\
        "v_readlane_b32 %7, %0, 63\n\t"                                       \
        "v_readlane_b32 %8, %1, 63\n\t"                                       \
        "v_readlane_b32 %9, %2, 63\n\t"                                       \
        "v_readlane_b32 %10, %3, 63\n\t"                                      \
        "v_readlane_b32 %11, %4, 63\n\t"                                      \
        "v_readlane_b32 %12, %5, 63\n\t"                                      \
        "v_readlane_b32 %13, %6, 63\n\t"                                      \
        "s_nop 1"                                                             \
        : "=&v"(r0), "=&v"(r1), "=&v"(r2), "=&v"(r3),                         \
          "=&v"(r4), "=&v"(r5), "=&v"(r6),                                    \
          "=s"(m0), "=s"(m1), "=s"(m2), "=s"(m3),                             \
          "=s"(m4), "=s"(m5), "=s"(m6)                                        \
        : "v"(v0), "v"(v1), "v"(v2), "v"(v3), "v"(v4), "v"(v5), "v"(v6));     \
  }

// 7-column interleaved 64-lane SUM reduce; e0..e6 clobbered; sums -> SGPRs.
#define WAVE_SUM7(e0,e1,e2,e3,e4,e5,e6, s0_,s1_,s2_,s3_,s4_,s5_,s6_)          \
    asm("s_nop 1\n\t"                                                         \
        "v_add_f32_dpp %0, %0, %0 row_shr:1 row_mask:0xf bank_mask:0xf\n\t"   \
        "v_add_f32_dpp %1, %1, %1 row_shr:1 row_mask:0xf bank_mask:0xf\n\t"   \
        "v_add_f32_dpp %2, %2, %2 row_shr:1 row_mask:0xf bank_mask:0xf\n\t"   \
        "v_add_f32_dpp %3, %3, %3 row_shr:1 row_mask:0xf bank_mask:0xf\n\t"   \
        "v_add_f32_dpp %4, %4, %4 row_shr:1 row_mask:0xf bank_mask:0xf\n\t"   \
        "v_add_f32_dpp %5, %5, %5 row_shr:1 row_mask:0xf bank_mask:0xf\n\t"   \
        "v_add_f32_dpp %6, %6, %6 row_shr:1 row_mask:0xf bank_mask:0xf\n\t"   \
        "v_add_f32_dpp %0, %0, %0 row_shr:2 row_mask:0xf bank_mask:0xf\n\t"   \
        "v_add_f32_dpp %1, %1, %1 row_shr:2 row_mask:0xf bank_mask:0xf\n\t"   \
        "v_add_f32_dpp %2, %2, %2 row_shr:2 row_mask:0xf bank_mask:0xf\n\t"   \
        "v_add_f32_dpp %3, %3, %3 row_shr:2 row_mask:0xf bank_mask:0xf\n\t"   \
        "v_add_f32_dpp %4, %4, %4 row_shr:2 row_mask:0xf bank_mask:0xf\n\t"   \
        "v_add_f32_dpp %5, %5, %5 row_shr:2 row_mask:0xf bank_mask:0xf\n\t"   \
        "v_add_f32_dpp %6, %6, %6 row_shr:2 row_mask:0xf bank_mask:0xf\n\t"   \
        "v_add_f32_dpp %0, %0, %0 row_shr:4 row_mask:0xf bank_mask:0xf\n\t"   \
        "v_add_f32_dpp %1, %1, %1 row_shr:4 row_mask:0xf bank_mask:0xf\n\t"   \
        "v_add_f32_dpp %2, %2, %2 row_shr:4 row_mask:0xf bank_mask:0xf\n\t"   \
        "v_add_f32_dpp %3, %3, %3 row_shr:4 row_mask:0xf bank_mask:0xf\n\t"   \
        "v_add_f32_dpp %4, %4, %4 row_shr:4 row_mask:0xf bank_mask:0xf\n\t"   \
        "v_add_f32_dpp %5, %5, %5 row_shr:4 row_mask:0xf bank_mask:0xf\n\t"   \
        "v_add_f32_dpp %6, %6, %6 row_shr:4 row_mask:0xf bank_mask:0xf\n\t"   \
        "v_add_f32_dpp %0, %0, %0 row_shr:8 row_mask:0xf bank_mask:0xf\n\t"   \
        "v_add_f32_dpp %1, %1, %1 row_shr:8 row_mask:0xf bank_mask:0xf\n\t"   \
        "v_add_f32_dpp %2, %2, %2 row_shr:8 row_mask:0xf bank_mask:0xf\n\t"   \
        "v_add_f32_dpp %3, %3, %3 row_shr:8 row_mask:0xf bank_mask:0xf\n\t"   \
        "v_add_f32_dpp %4, %4, %4 row_shr:8 row_mask:0xf bank_mask:0xf\n\t"   \
        "v_add_f32_dpp %5, %5, %5 row_shr:8 row_mask:0xf bank_mask:0xf\n\t"   \
        "v_add_f32_dpp %6, %6, %6 row_shr:8 row_mask:0xf bank_mask:0xf\n\t"   \
        "v_add_f32_dpp %0, %0, %0 row_bcast:15 row_mask:0xa bank_mask:0xf\n\t"\
        "v_add_f32_dpp %1, %1, %1 row_bcast:15 row_mask:0xa bank_mask:0xf\n\t"\
        "v_add_f32_dpp %2, %2, %2 row_bcast:15 row_mask:0xa bank_mask:0xf\n\t"\
        "v_add_f32_dpp %3, %3, %3 row_bcast:15 row_mask:0xa bank_mask:0xf\n\t"\
        "v_add_f32_dpp %4, %4, %4 row_bcast:15 row_mask:0xa bank_mask:0xf\n\t"\
        "v_add_f32_dpp %5, %5, %5 row_bcast:15 row_mask:0xa bank_mask:0xf\n\t"\
        "v_add_f32_dpp %6, %6, %6 row_bcast:15 row_mask:0xa bank_mask:0xf\n\t"\
        "v_add_f32_dpp %0, %0, %0 row_bcast:31 row_mask:0xc bank_mask:0xf\n\t"\
        "v_add_f32_dpp %1, %1, %1 row_bcast:31 row_mask:0xc bank_mask:0xf\n\t"\
        "v_add_f32_dpp %2, %2, %2 row_bcast:31 row_mask:0xc bank_mask:0xf\n\t"\
        "v_add_f32_dpp %3, %3, %3 row_bcast:31 row_mask:0xc bank_mask:0xf\n\t"\
        "v_add_f32_dpp %4, %4, %4 row_bcast:31 row_mask:0xc bank_mask:0xf\n\t"\
        "v_add_f32_dpp %5, %5, %5 row_bcast:31 row_mask:0xc bank_mask:0xf\n\t"\
        "v_add_f32_dpp %6, %6, %6 row_bcast:31 row_mask:0xc bank_mask:0xf\n\t"\
        "v_readlane_b32 %7, %0, 63\n\t"                                       \
        "v_readlane_b32 %8, %1, 63\n\t"                                       \
        "v_readlane_b32 %9, %2, 63\n\t"                                       \
        "v_readlane_b32 %10, %3, 63\n\t"                                      \
        "v_readlane_b32 %11, %4, 63\n\t"                                      \
        "v_readlane_b32 %12, %5, 63\n\t"                                      \
        "v_readlane_b32 %13, %6, 63\n\t"                                      \
        "s_nop 1"                                                             \
        : "+v"(e0), "+v"(e1), "+v"(e2), "+v"(e3),                             \
          "+v"(e4), "+v"(e5), "+v"(e6),                                       \
          "=s"(s0_), "=s"(s1_), "=s"(s2_), "=s"(s3_),                         \
          "=s"(s4_), "=s"(s5_), "=s"(s6_))

__global__ __launch_bounds__(64) void sinkhorn_kernel(
    const float* __restrict__ theta,  // [64,7]
    const float* __restrict__ phi,    // [7]
    const float* __restrict__ n,      // [64]
    const float* __restrict__ sens,   // [64]
    const float* __restrict__ err,    // [7]
    float* __restrict__ out)          // [64,7]
{
    const int lane = threadIdx.x;     // one wave: lane == row

    const float ni = n[lane];
    const float si = sens[lane];

    // Base-2 domain. K2 = (theta - C)*log2e/EPS.
    const float kscale = LOG2E_ / EPS_;
    float K2[NB];
    #pragma unroll
    for (int j = 0; j < NB; ++j)
        K2[j] = (theta[lane * NB + j] - ni * si * err[j]) * kscale;

    const float nsum   = wave_sum_bcast(ni);
    const float log_a2 = log2_hw(ni / nsum + TINY_);

    // log_b2 = log2(softmax(phi) + TINY)  (uniform; per lane)
    float t2v[NB];
    #pragma unroll
    for (int j = 0; j < NB; ++j) t2v[j] = phi[j] * LOG2E_;
    float pmax = t2v[0];
    #pragma unroll
    for (int j = 1; j < NB; ++j) pmax = fmaxf(pmax, t2v[j]);
    float psum = 0.f;
    #pragma unroll
    for (int j = 0; j < NB; ++j) psum += exp2_hw(t2v[j] - pmax);
    const float lps = log2_hw(psum);
    float log_b2[NB], cb[NB];
    #pragma unroll
    for (int j = 0; j < NB; ++j) {
        log_b2[j] = log2_hw(exp2_hw(t2v[j] - pmax - lps) + TINY_);
        cb[j]     = log_b2[j] - log_a2;
    }

    // Single state vector: t_j = K2_j - lse_j + f   (per lane).
    float t[NB];
    #pragma unroll
    for (int j = 0; j < NB; ++j) t[j] = K2[j] - log_b2[j];

    const float LOF = __int_as_float(0x0D800000);  // 2^-100
    const float HIF = __int_as_float(0x71800000);  // 2^+100
    const unsigned LO = 0x0D800000u, HI = 0x71800000u;
    // Convergence band: ss in 2^(+-0.015) -> bits of ~0.98966 / ~1.01046
    const unsigned CLO = 0x3F7D5A5Cu, CHI = 0x3F8156C1u;

    int okcnt = 0;

    for (int it = 0; it < ITERS_; ++it) {
        // Row lse with stale shift (shift = 0 in t-coordinates).
        float a0 = t[0] + cb[0], a1 = t[1] + cb[1], a2 = t[2] + cb[2],
              a3 = t[3] + cb[3], a4 = t[4] + cb[4], a5 = t[5] + cb[5],
              a6 = t[6] + cb[6];
        float s = ((exp2_hw(a0) + exp2_hw(a1)) + (exp2_hw(a2) + exp2_hw(a3)))
                + ((exp2_hw(a4) + exp2_hw(a5)) + exp2_hw(a6));
        float L;
        const bool ok = (s >= LOF) && (s <= HIF);   // NaN/inf -> false
        if (__ballot(ok) == ~0ull) {
            L = log2_hw(s);
        } else {
            float m = fmaxf(fmaxf(fmaxf(a0, a1), fmaxf(a2, a3)),
                            fmaxf(fmaxf(a4, a5), a6));
            float s2 = ((exp2_hw(a0 - m) + exp2_hw(a1 - m))
                      + (exp2_hw(a2 - m) + exp2_hw(a3 - m)))
                     + ((exp2_hw(a4 - m) + exp2_hw(a5 - m)) + exp2_hw(a6 - m));
            L = m + log2_hw(s2);
        }
        // Row residual: at the fixed point every row sum s == 1 -> L == 0.
        const unsigned long long rowok = __ballot(fabsf(L) < 0.015f);

        // Column lse with stale shift (shift = old lse, baked into t):
        float q0 = t[0] - L, q1 = t[1] - L, q2 = t[2] - L, q3 = t[3] - L,
              q4 = t[4] - L, q5 = t[5] - L, q6 = t[6] - L;
        float e0 = exp2_hw(q0), e1 = exp2_hw(q1), e2 = exp2_hw(q2),
              e3 = exp2_hw(q3), e4 = exp2_hw(q4), e5 = exp2_hw(q5),
              e6 = exp2_hw(q6);
        float ss0, ss1, ss2, ss3, ss4, ss5, ss6;
        WAVE_SUM7(e0, e1, e2, e3, e4, e5, e6, ss0, ss1, ss2, ss3, ss4, ss5, ss6);

        // SALU guard on the 7 uniform sums (positive-float bits order as uints)
        const unsigned u0 = __float_as_uint(ss0), u1 = __float_as_uint(ss1),
                       u2 = __float_as_uint(ss2), u3 = __float_as_uint(ss3),
                       u4 = __float_as_uint(ss4), u5 = __float_as_uint(ss5),
                       u6 = __float_as_uint(ss6);
        const unsigned umin = min(min(min(u0, u1), min(u2, u3)),
                                  min(min(u4, u5), u6));
        const unsigned umax = max(max(max(u0, u1), max(u2, u3)),
                                  max(max(u4, u5), u6));
        if (umin < LO || umax > HI) {
            // exact column path: fresh max shift
            float M0, M1, M2, M3, M4, M5, M6;
            WAVE_MAX7(q0, q1, q2, q3, q4, q5, q6, M0, M1, M2, M3, M4, M5, M6);
            e0 = exp2_hw(q0 - M0); e1 = exp2_hw(q1 - M1);
            e2 = exp2_hw(q2 - M2); e3 = exp2_hw(q3 - M3);
            e4 = exp2_hw(q4 - M4); e5 = exp2_hw(q5 - M5);
            e6 = exp2_hw(q6 - M6);
            WAVE_SUM7(e0, e1, e2, e3, e4, e5, e6, ss0, ss1, ss2, ss3, ss4, ss5, ss6);
            t[0] = q0 - (M0 + log2_hw(ss0)); t[1] = q1 - (M1 + log2_hw(ss1));
            t[2] = q2 - (M2 + log2_hw(ss2)); t[3] = q3 - (M3 + log2_hw(ss3));
            t[4] = q4 - (M4 + log2_hw(ss4)); t[5] = q5 - (M5 + log2_hw(ss5));
            t[6] = q6 - (M6 + log2_hw(ss6));
        } else {
            t[0] = q0 - log2_hw(ss0); t[1] = q1 - log2_hw(ss1);
            t[2] = q2 - log2_hw(ss2); t[3] = q3 - log2_hw(ss3);
            t[4] = q4 - log2_hw(ss4); t[5] = q5 - log2_hw(ss5);
            t[6] = q6 - log2_hw(ss6);
        }

        // Column residual: at the fixed point every ss_j == 1 (within
        // 2^+-0.015). Combined with the row residual: the Sinkhorn marginal
        // violation is at the ulp-noise floor -> we're at the same attractor
        // the 200-iter reference converges to. Require 3 consecutive passes.
        const bool colok = (umin >= CLO) && (umax <= CHI);
        okcnt = (rowok == ~0ull && colok && it > 20) ? okcnt + 1 : 0;
        if (okcnt >= 3) break;   // uniform branch (SGPR values only)
    }

    // ---- P = 2^(t + log_b2); normalize with TINY ----
    const float NI = __int_as_float(0xff800000);
    float x[NB];
    float m = NI;
    #pragma unroll
    for (int j = 0; j < NB; ++j) {
        x[j] = t[j] + log_b2[j];
        m = fmaxf(m, x[j]);
    }
    m = wave_max_bcast(m);

    float p[NB];
    float s = 0.f;
    #pragma unroll
    for (int j = 0; j < NB; ++j) {
        p[j] = exp2_hw(x[j] - m);
        s += p[j];
    }
    s = wave_sum_bcast(s);

    // denom = (P.sum() + TINY)*2^-m ; log2(1e-40) = -132.877
    const float inv = 1.0f / (s + exp2_hw(-132.87712379549449f - m));
    #pragma unroll
    for (int j = 0; j < NB; ++j)
        out[lane * NB + j] = p[j] * inv;
}

extern "C" void kernel_launch(void* const* d_in, const int* in_sizes, int n_in,
                              void* d_out, int out_size, void* d_ws, size_t ws_size,
                              hipStream_t stream) {
    const float* theta = (const float*)d_in[0];
    const float* phi   = (const float*)d_in[1];
    const float* n     = (const float*)d_in[2];
    const float* sens  = (const float*)d_in[3];
    const float* err   = (const float*)d_in[4];
    float* out = (float*)d_out;

    sinkhorn_kernel<<<1, 64, 0, stream>>>(theta, phi, n, sens, err, out);
}

// Round 10
// 135.114 us; speedup vs baseline: 1.0026x; 1.0026x over previous
//
#include <hip/hip_runtime.h>
#include <math.h>

#define NB 7
#define EPS_ 0.02f
#define ITERS_ 200
#define TINY_ 1e-40f
#define LOG2E_ 1.4426950408889634f
#define LN2_   0.6931471805599453f
#define WTOL_  1.5e-5f   // mass-weighted marginal residual (log2 units)

// Bare hardware transcendentals (base-2 domain).
__device__ __forceinline__ float exp2_hw(float x) {
#if __has_builtin(__builtin_amdgcn_exp2f)
    return __builtin_amdgcn_exp2f(x);
#else
    return __expf(x * LN2_);
#endif
}
__device__ __forceinline__ float log2_hw(float x) {
#if __has_builtin(__builtin_amdgcn_logf)
    return __builtin_amdgcn_logf(x);
#else
    return __logf(x) * LOG2E_;
#endif
}

// ---- DPP helpers (prologue/epilogue only) ----
template <int CTRL>
__device__ __forceinline__ float dpp_ident(float identity, float x) {
    return __int_as_float(__builtin_amdgcn_update_dpp(
        __float_as_int(identity), __float_as_int(x), CTRL, 0xF, 0xF, false));
}
__device__ __forceinline__ float readlane63(float x) {
    return __int_as_float(__builtin_amdgcn_readlane(__float_as_int(x), 63));
}
__device__ __forceinline__ float wave_sum_bcast(float s) {
    s += dpp_ident<0x111>(0.f, s);
    s += dpp_ident<0x112>(0.f, s);
    s += dpp_ident<0x114>(0.f, s);
    s += dpp_ident<0x118>(0.f, s);
    s += dpp_ident<0x142>(0.f, s);
    s += dpp_ident<0x143>(0.f, s);
    return readlane63(s);
}
__device__ __forceinline__ float wave_max_bcast(float m) {
    const float NI = __int_as_float(0xff800000);
    m = fmaxf(m, dpp_ident<0x111>(NI, m));
    m = fmaxf(m, dpp_ident<0x112>(NI, m));
    m = fmaxf(m, dpp_ident<0x114>(NI, m));
    m = fmaxf(m, dpp_ident<0x118>(NI, m));
    m = fmaxf(m, dpp_ident<0x142>(NI, m));
    m = fmaxf(m, dpp_ident<0x143>(NI, m));
    return readlane63(m);
}

// 7-column interleaved 64-lane MAX reduce (keep-old DPP = identity-free).
#define WAVE_MAX7(v0,v1,v2,v3,v4,v5,v6, m0,m1,m2,m3,m4,m5,m6)                 \
  {                                                                           \
    float r0,r1,r2,r3,r4,r5,r6;                                               \
    asm("v_mov_b32 %0, %14\n\t"                                               \
        "v_mov_b32 %1, %15\n\t"                                               \
        "v_mov_b32 %2, %16\n\t"                                               \
        "v_mov_b32 %3, %17\n\t"                                               \
        "v_mov_b32 %4, %18\n\t"                                               \
        "v_mov_b32 %5, %19\n\t"                                               \
        "v_mov_b32 %6, %20\n\t"                                               \
        "v_max_f32_dpp %0, %0, %0 row_shr:1 row_mask:0xf bank_mask:0xf\n\t"   \
        "v_max_f32_dpp %1, %1, %1 row_shr:1 row_mask:0xf bank_mask:0xf\n\t"   \
        "v_max_f32_dpp %2, %2, %2 row_shr:1 row_mask:0xf bank_mask:0xf\n\t"   \
        "v_max_f32_dpp %3, %3, %3 row_shr:1 row_mask:0xf bank_mask:0xf\n\t"   \
        "v_max_f32_dpp %4, %4, %4 row_shr:1 row_mask:0xf bank_mask:0xf\n\t"   \
        "v_max_f32_dpp %5, %5, %5 row_shr:1 row_mask:0xf bank_mask:0xf\n\t"   \
        "v_max_f32_dpp %6, %6, %6 row_shr:1 row_mask:0xf bank_mask:0xf\n\t"   \
        "v_max_f32_dpp %0, %0, %0 row_shr:2 row_mask:0xf bank_mask:0xf\n\t"   \
        "v_max_f32_dpp %1, %1, %1 row_shr:2 row_mask:0xf bank_mask:0xf\n\t"   \
        "v_max_f32_dpp %2, %2, %2 row_shr:2 row_mask:0xf bank_mask:0xf\n\t"   \
        "v_max_f32_dpp %3, %3, %3 row_shr:2 row_mask:0xf bank_mask:0xf\n\t"   \
        "v_max_f32_dpp %4, %4, %4 row_shr:2 row_mask:0xf bank_mask:0xf\n\t"   \
        "v_max_f32_dpp %5, %5, %5 row_shr:2 row_mask:0xf bank_mask:0xf\n\t"   \
        "v_max_f32_dpp %6, %6, %6 row_shr:2 row_mask:0xf bank_mask:0xf\n\t"   \
        "v_max_f32_dpp %0, %0, %0 row_shr:4 row_mask:0xf bank_mask:0xf\n\t"   \
        "v_max_f32_dpp %1, %1, %1 row_shr:4 row_mask:0xf bank_mask:0xf\n\t"   \
        "v_max_f32_dpp %2, %2, %2 row_shr:4 row_mask:0xf bank_mask:0xf\n\t"   \
        "v_max_f32_dpp %3, %3, %3 row_shr:4 row_mask:0xf bank_mask:0xf\n\t"   \
        "v_max_f32_dpp %4, %4, %4 row_shr:4 row_mask:0xf bank_mask:0xf\n\t"   \
        "v_max_f32_dpp %5, %5, %5 row_shr:4 row_mask:0xf bank_mask:0xf\n\t"   \
        "v_max_f32_dpp %6, %6, %6 row_shr:4 row_mask:0xf bank_mask:0xf\n\t"   \
        "v_max_f32_dpp %0, %0, %0 row_shr:8 row_mask:0xf bank_mask:0xf\n\t"   \
        "v_max_f32_dpp %1, %1, %1 row_shr:8 row_mask:0xf bank_mask:0xf\n\t"   \
        "v_max_f32_dpp %2, %2, %2 row_shr:8 row_mask:0xf bank_mask:0xf\n\t"   \
        "v_max_f32_dpp %3, %3, %3 row_shr:8 row_mask:0xf bank_mask:0xf\n\t"   \
        "v_max_f32_dpp %4, %4, %4 row_shr:8 row_mask:0xf bank_mask:0xf\n\t"   \
        "v_max_f32_dpp %5, %5, %5 row_shr:8 row_mask:0xf bank_mask:0xf\n\t"   \
        "v_max_f32_dpp %6, %6, %6 row_shr:8 row_mask:0xf bank_mask:0xf\n\t"   \
        "v_max_f32_dpp %0, %0, %0 row_bcast:15 row_mask:0xa bank_mask:0xf\n\t"\
        "v_max_f32_dpp %1, %1, %1 row_bcast:15 row_mask:0xa bank_mask:0xf\n\t"\
        "v_max_f32_dpp %2, %2, %2 row_bcast:15 row_mask:0xa bank_mask:0xf\n\t"\
        "v_max_f32_dpp %3, %3, %3 row_bcast:15 row_mask:0xa bank_mask:0xf\n\t"\
        "v_max_f32_dpp %4, %4, %4 row_bcast:15 row_mask:0xa bank_mask:0xf\n\t"\
        "v_max_f32_dpp %5, %5, %5 row_bcast:15 row_mask:0xa bank_mask:0xf\n\t"\
        "v_max_f32_dpp %6, %6, %6 row_bcast:15 row_mask:0xa bank_mask:0xf\n\t"\
        "v_max_f32_dpp %0, %0, %0 row_bcast:31 row_mask:0xc bank_mask:0xf\n\t"\
        "v_max_f32_dpp %1, %1, %1 row_bcast:31 row_mask:0xc bank_mask:0xf\n\t"\
        "v_max_f32_dpp %2, %2, %2 row_bcast:31 row_mask:0xc bank_mask:0xf\n\t"\
        "v_max_f32_dpp %3, %3, %3 row_bcast:31 row_mask:0xc bank_mask:0xf\n\t"\
        "v_max_f32_dpp %4, %4, %4 row_bcast:31 row_mask:0xc bank_mask:0xf\n\t"\
        "v_max_f32_dpp %5, %5, %5 row_bcast:31 row_mask:0xc bank_mask:0xf\n\t"\
        "v_max_f32_dpp %6, %6, %6 row_bcast:31 row_mask:0xc bank_mask:0xf\n\t"\
        "v_readlane_b32 %7, %0, 63\n\t"                                       \
        "v_readlane_b32 %8, %1, 63\n\t"                                       \
        "v_readlane_b32 %9, %2, 63\n\t"                                       \
        "v_readlane_b32 %10, %3, 63\n\t"                                      \
        "v_readlane_b32 %11, %4, 63\n\t"                                      \
        "v_readlane_b32 %12, %5, 63\n\t"                                      \
        "v_readlane_b32 %13, %6, 63\n\t"                                      \
        "s_nop 1"                                                             \
        : "=&v"(r0), "=&v"(r1), "=&v"(r2), "=&v"(r3),                         \
          "=&v"(r4), "=&v"(r5), "=&v"(r6),                                    \
          "=s"(m0), "=s"(m1), "=s"(m2), "=s"(m3),                             \
          "=s"(m4), "=s"(m5), "=s"(m6)                                        \
        : "v"(v0), "v"(v1), "v"(v2), "v"(v3), "v"(v4), "v"(v5), "v"(v6));     \
  }

// 7-column interleaved 64-lane SUM reduce; e0..e6 clobbered; sums -> SGPRs.
#define WAVE_SUM7(e0,e1,e2,e3,e4,e5,e6, s0_,s1_,s2_,s3_,s4_,s5_,s6_)          \
    asm("s_nop 1\n\t"                                                         \
        "v_add_f32_dpp %0, %0, %0 row_shr:1 row_mask:0xf bank_mask:0xf\n\t"   \
        "v_add_f32_dpp %1, %1, %1 row_shr:1 row_mask:0xf bank_mask:0xf\n\t"   \
        "v_add_f32_dpp %2, %2, %2 row_shr:1 row_mask:0xf bank_mask:0xf\n\t"   \
        "v_add_f32_dpp %3, %3, %3 row_shr:1 row_mask:0xf bank_mask:0xf\n\t"   \
        "v_add_f32_dpp %4, %4, %4 row_shr:1 row_mask:0xf bank_mask:0xf\n\t"   \
        "v_add_f32_dpp %5, %5, %5 row_shr:1 row_mask:0xf bank_mask:0xf\n\t"   \
        "v_add_f32_dpp %6, %6, %6 row_shr:1 row_mask:0xf bank_mask:0xf\n\t"   \
        "v_add_f32_dpp %0, %0, %0 row_shr:2 row_mask:0xf bank_mask:0xf\n\t"   \
        "v_add_f32_dpp %1, %1, %1 row_shr:2 row_mask:0xf bank_mask:0xf\n\t"   \
        "v_add_f32_dpp %2, %2, %2 row_shr:2 row_mask:0xf bank_mask:0xf\n\t"   \
        "v_add_f32_dpp %3, %3, %3 row_shr:2 row_mask:0xf bank_mask:0xf\n\t"   \
        "v_add_f32_dpp %4, %4, %4 row_shr:2 row_mask:0xf bank_mask:0xf\n\t"   \
        "v_add_f32_dpp %5, %5, %5 row_shr:2 row_mask:0xf bank_mask:0xf\n\t"   \
        "v_add_f32_dpp %6, %6, %6 row_shr:2 row_mask:0xf bank_mask:0xf\n\t"   \
        "v_add_f32_dpp %0, %0, %0 row_shr:4 row_mask:0xf bank_mask:0xf\n\t"   \
        "v_add_f32_dpp %1, %1, %1 row_shr:4 row_mask:0xf bank_mask:0xf\n\t"   \
        "v_add_f32_dpp %2, %2, %2 row_shr:4 row_mask:0xf bank_mask:0xf\n\t"   \
        "v_add_f32_dpp %3, %3, %3 row_shr:4 row_mask:0xf bank_mask:0xf\n\t"   \
        "v_add_f32_dpp %4, %4, %4 row_shr:4 row_mask:0xf bank_mask:0xf\n\t"   \
        "v_add_f32_dpp %5, %5, %5 row_shr:4 row_mask:0xf bank_mask:0xf\n\t"   \
        "v_add_f32_dpp %6, %6, %6 row_shr:4 row_mask:0xf bank_mask:0xf\n\t"   \
        "v_add_f32_dpp %0, %0, %0 row_shr:8 row_mask:0xf bank_mask:0xf\n\t"   \
        "v_add_f32_dpp %1, %1, %1 row_shr:8 row_mask:0xf bank_mask:0xf\n\t"   \
        "v_add_f32_dpp %2, %2, %2 row_shr:8 row_mask:0xf bank_mask:0xf\n\t"   \
        "v_add_f32_dpp %3, %3, %3 row_shr:8 row_mask:0xf bank_mask:0xf\n\t"   \
        "v_add_f32_dpp %4, %4, %4 row_shr:8 row_mask:0xf bank_mask:0xf\n\t"   \
        "v_add_f32_dpp %5, %5, %5 row_shr:8 row_mask:0xf bank_mask:0xf\n\t"   \
        "v_add_f32_dpp %6, %6, %6 row_shr:8 row_mask:0xf bank_mask:0xf\n\t"   \
        "v_add_f32_dpp %0, %0, %0 row_bcast:15 row_mask:0xa bank_mask:0xf\n\t"\
        "v_add_f32_dpp %1, %1, %1 row_bcast:15 row_mask:0xa bank_mask:0xf\n\t"\
        "v_add_f32_dpp %2, %2, %2 row_bcast:15 row_mask:0xa bank_mask:0xf\n\t"\
        "v_add_f32_dpp %3, %3, %3 row_bcast:15 row_mask:0xa bank_mask:0xf\n\t"\
        "v_add_f32_dpp %4, %4, %4 row_bcast:15 row_mask:0xa bank_mask:0xf\n\t"\
        "v_add_f32_dpp %5, %5, %5 row_bcast:15 row_mask:0xa bank_mask:0xf\n\t"\
        "v_add_f32_dpp %6, %6, %6 row_bcast:15 row_mask:0xa bank_mask:0xf\n\t"\
        "v_add_f32_dpp %0, %0, %0 row_bcast:31 row_mask:0xc bank_mask:0xf\n\t"\
        "v_add_f32_dpp %1, %1, %1 row_bcast:31 row_mask:0xc bank_mask:0xf\n\t"\
        "v_add_f32_dpp %2, %2, %2 row_bcast:31 row_mask:0xc bank_mask:0xf\n\t"\
        "v_add_f32_dpp %3, %3, %3 row_bcast:31 row_mask:0xc bank_mask:0xf\n\t"\
        "v_add_f32_dpp %4, %4, %4 row_bcast:31 row_mask:0xc bank_mask:0xf\n\t"\
        "v_add_f32_dpp %5, %5, %5 row_bcast:31 row_mask:0xc bank_mask:0xf\n\t"\
        "v_add_f32_dpp %6, %6, %6 row_bcast:31 row_mask:0xc bank_mask:0xf\n\t"\
        "v_readlane_b32 %7, %0, 63\n\t"                                       \
        "v_readlane_b32 %8, %1, 63\n\t"                                       \
        "v_readlane_b32 %9, %2, 63\n\t"                                       \
        "v_readlane_b32 %10, %3, 63\n\t"                                      \
        "v_readlane_b32 %11, %4, 63\n\t"                                      \
        "v_readlane_b32 %12, %5, 63\n\t"                                      \
        "v_readlane_b32 %13, %6, 63\n\t"                                      \
        "s_nop 1"                                                             \
        : "+v"(e0), "+v"(e1), "+v"(e2), "+v"(e3),                             \
          "+v"(e4), "+v"(e5), "+v"(e6),                                       \
          "=s"(s0_), "=s"(s1_), "=s"(s2_), "=s"(s3_),                         \
          "=s"(s4_), "=s"(s5_), "=s"(s6_))

__global__ __launch_bounds__(64) void sinkhorn_kernel(
    const float* __restrict__ theta,  // [64,7]
    const float* __restrict__ phi,    // [7]
    const float* __restrict__ n,      // [64]
    const float* __restrict__ sens,   // [64]
    const float* __restrict__ err,    // [7]
    float* __restrict__ out)          // [64,7]
{
    const int lane = threadIdx.x;     // one wave: lane == row

    const float ni = n[lane];
    const float si = sens[lane];

    // Base-2 domain. K2 = (theta - C)*log2e/EPS.
    const float kscale = LOG2E_ / EPS_;
    float K2[NB];
    #pragma unroll
    for (int j = 0; j < NB; ++j)
        K2[j] = (theta[lane * NB + j] - ni * si * err[j]) * kscale;

    const float nsum   = wave_sum_bcast(ni);
    const float av     = ni / nsum;              // row mass a_i (per lane)
    const float log_a2 = log2_hw(av + TINY_);

    // b = softmax(phi); log_b2 = log2(b + TINY)  (uniform; per lane)
    float t2v[NB];
    #pragma unroll
    for (int j = 0; j < NB; ++j) t2v[j] = phi[j] * LOG2E_;
    float pmax = t2v[0];
    #pragma unroll
    for (int j = 1; j < NB; ++j) pmax = fmaxf(pmax, t2v[j]);
    float psum = 0.f;
    #pragma unroll
    for (int j = 0; j < NB; ++j) psum += exp2_hw(t2v[j] - pmax);
    const float lps = log2_hw(psum);
    float bv[NB], log_b2[NB], cb[NB];
    #pragma unroll
    for (int j = 0; j < NB; ++j) {
        bv[j]     = exp2_hw(t2v[j] - pmax - lps);   // column mass b_j
        log_b2[j] = log2_hw(bv[j] + TINY_);
        cb[j]     = log_b2[j] - log_a2;
    }

    // Single state vector: t_j = K2_j - lse_j + f   (per lane).
    float t[NB];
    #pragma unroll
    for (int j = 0; j < NB; ++j) t[j] = K2[j] - log_b2[j];

    const float LOF = __int_as_float(0x0D800000);  // 2^-100
    const float HIF = __int_as_float(0x71800000);  // 2^+100
    const unsigned LO = 0x0D800000u, HI = 0x71800000u;

    int okcnt = 0;

    for (int it = 0; it < ITERS_; ++it) {
        // Row lse with stale shift (shift = 0 in t-coordinates).
        float a0 = t[0] + cb[0], a1 = t[1] + cb[1], a2 = t[2] + cb[2],
              a3 = t[3] + cb[3], a4 = t[4] + cb[4], a5 = t[5] + cb[5],
              a6 = t[6] + cb[6];
        float s = ((exp2_hw(a0) + exp2_hw(a1)) + (exp2_hw(a2) + exp2_hw(a3)))
                + ((exp2_hw(a4) + exp2_hw(a5)) + exp2_hw(a6));
        float L;
        const bool ok = (s >= LOF) && (s <= HIF);   // NaN/inf -> false
        if (__ballot(ok) == ~0ull) {
            L = log2_hw(s);
        } else {
            float m = fmaxf(fmaxf(fmaxf(a0, a1), fmaxf(a2, a3)),
                            fmaxf(fmaxf(a4, a5), a6));
            float s2 = ((exp2_hw(a0 - m) + exp2_hw(a1 - m))
                      + (exp2_hw(a2 - m) + exp2_hw(a3 - m)))
                     + ((exp2_hw(a4 - m) + exp2_hw(a5 - m)) + exp2_hw(a6 - m));
            L = m + log2_hw(s2);
        }

        // Column lse with stale shift (shift = old lse, baked into t):
        float q0 = t[0] - L, q1 = t[1] - L, q2 = t[2] - L, q3 = t[3] - L,
              q4 = t[4] - L, q5 = t[5] - L, q6 = t[6] - L;
        float e0 = exp2_hw(q0), e1 = exp2_hw(q1), e2 = exp2_hw(q2),
              e3 = exp2_hw(q3), e4 = exp2_hw(q4), e5 = exp2_hw(q5),
              e6 = exp2_hw(q6);
        float ss0, ss1, ss2, ss3, ss4, ss5, ss6;
        WAVE_SUM7(e0, e1, e2, e3, e4, e5, e6, ss0, ss1, ss2, ss3, ss4, ss5, ss6);

        // SALU guard on the 7 uniform sums (positive-float bits order as uints)
        const unsigned u0 = __float_as_uint(ss0), u1 = __float_as_uint(ss1),
                       u2 = __float_as_uint(ss2), u3 = __float_as_uint(ss3),
                       u4 = __float_as_uint(ss4), u5 = __float_as_uint(ss5),
                       u6 = __float_as_uint(ss6);
        const unsigned umin = min(min(min(u0, u1), min(u2, u3)),
                                  min(min(u4, u5), u6));
        const unsigned umax = max(max(max(u0, u1), max(u2, u3)),
                                  max(max(u4, u5), u6));
        float lg0, lg1, lg2, lg3, lg4, lg5, lg6;
        if (umin < LO || umax > HI) {
            // exact column path: fresh max shift (transient -> not converged)
            float M0, M1, M2, M3, M4, M5, M6;
            WAVE_MAX7(q0, q1, q2, q3, q4, q5, q6, M0, M1, M2, M3, M4, M5, M6);
            e0 = exp2_hw(q0 - M0); e1 = exp2_hw(q1 - M1);
            e2 = exp2_hw(q2 - M2); e3 = exp2_hw(q3 - M3);
            e4 = exp2_hw(q4 - M4); e5 = exp2_hw(q5 - M5);
            e6 = exp2_hw(q6 - M6);
            WAVE_SUM7(e0, e1, e2, e3, e4, e5, e6, ss0, ss1, ss2, ss3, ss4, ss5, ss6);
            t[0] = q0 - (M0 + log2_hw(ss0)); t[1] = q1 - (M1 + log2_hw(ss1));
            t[2] = q2 - (M2 + log2_hw(ss2)); t[3] = q3 - (M3 + log2_hw(ss3));
            t[4] = q4 - (M4 + log2_hw(ss4)); t[5] = q5 - (M5 + log2_hw(ss5));
            t[6] = q6 - (M6 + log2_hw(ss6));
            okcnt = 0;
        } else {
            lg0 = log2_hw(ss0); lg1 = log2_hw(ss1); lg2 = log2_hw(ss2);
            lg3 = log2_hw(ss3); lg4 = log2_hw(ss4); lg5 = log2_hw(ss5);
            lg6 = log2_hw(ss6);
            t[0] = q0 - lg0; t[1] = q1 - lg1; t[2] = q2 - lg2;
            t[3] = q3 - lg3; t[4] = q4 - lg4; t[5] = q5 - lg5;
            t[6] = q6 - lg6;

            // Mass-weighted convergence check, every 4th iteration.
            // Contribution of residuals to P: ~ a_i*|L_i| (rows),
            // ~ b_j*|lg_j| (cols), in log2 units. Low-mass rows may wander;
            // their P-impact is down-weighted exactly by a_i.
            if ((it & 3) == 3) {
                const bool rk = av * fabsf(L) < WTOL_;
                float cmax = bv[0] * fabsf(lg0);
                cmax = fmaxf(cmax, bv[1] * fabsf(lg1));
                cmax = fmaxf(cmax, bv[2] * fabsf(lg2));
                cmax = fmaxf(cmax, bv[3] * fabsf(lg3));
                cmax = fmaxf(cmax, bv[4] * fabsf(lg4));
                cmax = fmaxf(cmax, bv[5] * fabsf(lg5));
                cmax = fmaxf(cmax, bv[6] * fabsf(lg6));
                const bool allrows = (__ballot(rk) == ~0ull);
                const bool allcols = (__ballot(cmax < WTOL_) == ~0ull);
                okcnt = (allrows && allcols && it > 24) ? okcnt + 1 : 0;
                if (okcnt >= 2) break;   // uniform branch
            }
        }
    }

    // ---- P = 2^(t + log_b2); normalize with TINY ----
    const float NI = __int_as_float(0xff800000);
    float x[NB];
    float m = NI;
    #pragma unroll
    for (int j = 0; j < NB; ++j) {
        x[j] = t[j] + log_b2[j];
        m = fmaxf(m, x[j]);
    }
    m = wave_max_bcast(m);

    float p[NB];
    float s = 0.f;
    #pragma unroll
    for (int j = 0; j < NB; ++j) {
        p[j] = exp2_hw(x[j] - m);
        s += p[j];
    }
    s = wave_sum_bcast(s);

    // denom = (P.sum() + TINY)*2^-m ; log2(1e-40) = -132.877
    const float inv = 1.0f / (s + exp2_hw(-132.87712379549449f - m));
    #pragma unroll
    for (int j = 0; j < NB; ++j)
        out[lane * NB + j] = p[j] * inv;
}

extern "C" void kernel_launch(void* const* d_in, const int* in_sizes, int n_in,
                              void* d_out, int out_size, void* d_ws, size_t ws_size,
                              hipStream_t stream) {
    const float* theta = (const float*)d_in[0];
    const float* phi   = (const float*)d_in[1];
    const float* n     = (const float*)d_in[2];
    const float* sens  = (const float*)d_in[3];
    const float* err   = (const float*)d_in[4];
    float* out = (float*)d_out;

    sinkhorn_kernel<<<1, 64, 0, stream>>>(theta, phi, n, sens, err, out);
}

// Round 13
// 117.576 us; speedup vs baseline: 1.1522x; 1.1492x over previous
//
#include <hip/hip_runtime.h>
#include <math.h>

#define NB 7
#define EPS_ 0.02f
#define ITERS1_ 120   // log-domain phase (handles +-25k log2 transient exactly)
#define ITERS2_ 80    // multiplicative phase (flush-safe: residual@120 ~5 log2
                      // units; flushed entries would need +105 to matter)
#define TINY_ 1e-40f
#define LOG2E_ 1.4426950408889634f
#define LN2_   0.6931471805599453f

// Bare hardware transcendentals (base-2 domain).
__device__ __forceinline__ float exp2_hw(float x) {
#if __has_builtin(__builtin_amdgcn_exp2f)
    return __builtin_amdgcn_exp2f(x);
#else
    return __expf(x * LN2_);
#endif
}
__device__ __forceinline__ float log2_hw(float x) {
#if __has_builtin(__builtin_amdgcn_logf)
    return __builtin_amdgcn_logf(x);
#else
    return __logf(x) * LOG2E_;
#endif
}
__device__ __forceinline__ float rcp_hw(float x) {
#if __has_builtin(__builtin_amdgcn_rcpf)
    return __builtin_amdgcn_rcpf(x);
#else
    return 1.0f / x;
#endif
}

// ---- DPP helpers ----
template <int CTRL>
__device__ __forceinline__ float dpp_ident(float identity, float x) {
    return __int_as_float(__builtin_amdgcn_update_dpp(
        __float_as_int(identity), __float_as_int(x), CTRL, 0xF, 0xF, false));
}
__device__ __forceinline__ float readlane63(float x) {
    return __int_as_float(__builtin_amdgcn_readlane(__float_as_int(x), 63));
}
__device__ __forceinline__ float wave_sum_bcast(float s) {
    s += dpp_ident<0x111>(0.f, s);
    s += dpp_ident<0x112>(0.f, s);
    s += dpp_ident<0x114>(0.f, s);
    s += dpp_ident<0x118>(0.f, s);
    s += dpp_ident<0x142>(0.f, s);
    s += dpp_ident<0x143>(0.f, s);
    return readlane63(s);
}
__device__ __forceinline__ float wave_max_bcast(float m) {
    const float NI = __int_as_float(0xff800000);
    m = fmaxf(m, dpp_ident<0x111>(NI, m));
    m = fmaxf(m, dpp_ident<0x112>(NI, m));
    m = fmaxf(m, dpp_ident<0x114>(NI, m));
    m = fmaxf(m, dpp_ident<0x118>(NI, m));
    m = fmaxf(m, dpp_ident<0x142>(NI, m));
    m = fmaxf(m, dpp_ident<0x143>(NI, m));
    return readlane63(m);
}

// 7-column interleaved 64-lane MAX reduce (keep-old DPP = identity-free).
#define WAVE_MAX7(v0,v1,v2,v3,v4,v5,v6, m0,m1,m2,m3,m4,m5,m6)                 \
  {                                                                           \
    float r0,r1,r2,r3,r4,r5,r6;                                               \
    asm("v_mov_b32 %0, %14\n\t"                                               \
        "v_mov_b32 %1, %15\n\t"                                               \
        "v_mov_b32 %2, %16\n\t"                                               \
        "v_mov_b32 %3, %17\n\t"                                               \
        "v_mov_b32 %4, %18\n\t"                                               \
        "v_mov_b32 %5, %19\n\t"                                               \
        "v_mov_b32 %6, %20\n\t"                                               \
        "v_max_f32_dpp %0, %0, %0 row_shr:1 row_mask:0xf bank_mask:0xf\n\t"   \
        "v_max_f32_dpp %1, %1, %1 row_shr:1 row_mask:0xf bank_mask:0xf\n\t"   \
        "v_max_f32_dpp %2, %2, %2 row_shr:1 row_mask:0xf bank_mask:0xf\n\t"   \
        "v_max_f32_dpp %3, %3, %3 row_shr:1 row_mask:0xf bank_mask:0xf\n\t"   \
        "v_max_f32_dpp %4, %4, %4 row_shr:1 row_mask:0xf bank_mask:0xf\n\t"   \
        "v_max_f32_dpp %5, %5, %5 row_shr:1 row_mask:0xf bank_mask:0xf\n\t"   \
        "v_max_f32_dpp %6, %6, %6 row_shr:1 row_mask:0xf bank_mask:0xf\n\t"   \
        "v_max_f32_dpp %0, %0, %0 row_shr:2 row_mask:0xf bank_mask:0xf\n\t"   \
        "v_max_f32_dpp %1, %1, %1 row_shr:2 row_mask:0xf bank_mask:0xf\n\t"   \
        "v_max_f32_dpp %2, %2, %2 row_shr:2 row_mask:0xf bank_mask:0xf\n\t"   \
        "v_max_f32_dpp %3, %3, %3 row_shr:2 row_mask:0xf bank_mask:0xf\n\t"   \
        "v_max_f32_dpp %4, %4, %4 row_shr:2 row_mask:0xf bank_mask:0xf\n\t"   \
        "v_max_f32_dpp %5, %5, %5 row_shr:2 row_mask:0xf bank_mask:0xf\n\t"   \
        "v_max_f32_dpp %6, %6, %6 row_shr:2 row_mask:0xf bank_mask:0xf\n\t"   \
        "v_max_f32_dpp %0, %0, %0 row_shr:4 row_mask:0xf bank_mask:0xf\n\t"   \
        "v_max_f32_dpp %1, %1, %1 row_shr:4 row_mask:0xf bank_mask:0xf\n\t"   \
        "v_max_f32_dpp %2, %2, %2 row_shr:4 row_mask:0xf bank_mask:0xf\n\t"   \
        "v_max_f32_dpp %3, %3, %3 row_shr:4 row_mask:0xf bank_mask:0xf\n\t"   \
        "v_max_f32_dpp %4, %4, %4 row_shr:4 row_mask:0xf bank_mask:0xf\n\t"   \
        "v_max_f32_dpp %5, %5, %5 row_shr:4 row_mask:0xf bank_mask:0xf\n\t"   \
        "v_max_f32_dpp %6, %6, %6 row_shr:4 row_mask:0xf bank_mask:0xf\n\t"   \
        "v_max_f32_dpp %0, %0, %0 row_shr:8 row_mask:0xf bank_mask:0xf\n\t"   \
        "v_max_f32_dpp %1, %1, %1 row_shr:8 row_mask:0xf bank_mask:0xf\n\t"   \
        "v_max_f32_dpp %2, %2, %2 row_shr:8 row_mask:0xf bank_mask:0xf\n\t"   \
        "v_max_f32_dpp %3, %3, %3 row_shr:8 row_mask:0xf bank_mask:0xf\n\t"   \
        "v_max_f32_dpp %4, %4, %4 row_shr:8 row_mask:0xf bank_mask:0xf\n\t"   \
        "v_max_f32_dpp %5, %5, %5 row_shr:8 row_mask:0xf bank_mask:0xf\n\t"   \
        "v_max_f32_dpp %6, %6, %6 row_shr:8 row_mask:0xf bank_mask:0xf\n\t"   \
        "v_max_f32_dpp %0, %0, %0 row_bcast:15 row_mask:0xa bank_mask:0xf\n\t"\
        "v_max_f32_dpp %1, %1, %1 row_bcast:15 row_mask:0xa bank_mask:0xf\n\t"\
        "v_max_f32_dpp %2, %2, %2 row_bcast:15 row_mask:0xa bank_mask:0xf\n\t"\
        "v_max_f32_dpp %3, %3, %3 row_bcast:15 row_mask:0xa bank_mask:0xf\n\t"\
        "v_max_f32_dpp %4, %4, %4 row_bcast:15 row_mask:0xa bank_mask:0xf\n\t"\
        "v_max_f32_dpp %5, %5, %5 row_bcast:15 row_mask:0xa bank_mask:0xf\n\t"\
        "v_max_f32_dpp %6, %6, %6 row_bcast:15 row_mask:0xa bank_mask:0xf\n\t"\
        "v_max_f32_dpp %0, %0, %0 row_bcast:31 row_mask:0xc bank_mask:0xf\n\t"\
        "v_max_f32_dpp %1, %1, %1 row_bcast:31 row_mask:0xc bank_mask:0xf\n\t"\
        "v_max_f32_dpp %2, %2, %2 row_bcast:31 row_mask:0xc bank_mask:0xf\n\t"\
        "v_max_f32_dpp %3, %3, %3 row_bcast:31 row_mask:0xc bank_mask:0xf\n\t"\
        "v_max_f32_dpp %4, %4, %4 row_bcast:31 row_mask:0xc bank_mask:0xf\n\t"\
        "v_max_f32_dpp %5, %5, %5 row_bcast:31 row_mask:0xc bank_mask:0xf\n\t"\
        "v_max_f32_dpp %6, %6, %6 row_bcast:31 row_mask:0xc bank_mask:0xf\n\t"\
        "v_readlane_b32 %7, %0, 63\n\t"                                       \
        "v_readlane_b32 %8, %1, 63\n\t"                                       \
        "v_readlane_b32 %9, %2, 63\n\t"                                       \
        "v_readlane_b32 %10, %3, 63\n\t"                                      \
        "v_readlane_b32 %11, %4, 63\n\t"                                      \
        "v_readlane_b32 %12, %5, 63\n\t"                                      \
        "v_readlane_b32 %13, %6, 63\n\t"                                      \
        "s_nop 1"                                                             \
        : "=&v"(r0), "=&v"(r1), "=&v"(r2), "=&v"(r3),                         \
          "=&v"(r4), "=&v"(r5), "=&v"(r6),                                    \
          "=s"(m0), "=s"(m1), "=s"(m2), "=s"(m3),                             \
          "=s"(m4), "=s"(m5), "=s"(m6)                                        \
        : "v"(v0), "v"(v1), "v"(v2), "v"(v3), "v"(v4), "v"(v5), "v"(v6));     \
  }

// 7-column interleaved 64-lane SUM reduce; e0..e6 clobbered; sums -> SGPRs.
#define WAVE_SUM7(e0,e1,e2,e3,e4,e5,e6, s0_,s1_,s2_,s3_,s4_,s5_,s6_)          \
    asm("s_nop 1\n\t"                                                         \
        "v_add_f32_dpp %0, %0, %0 row_shr:1 row_mask:0xf bank_mask:0xf\n\t"   \
        "v_add_f32_dpp %1, %1, %1 row_shr:1 row_mask:0xf bank_mask:0xf\n\t"   \
        "v_add_f32_dpp %2, %2, %2 row_shr:1 row_mask:0xf bank_mask:0xf\n\t"   \
        "v_add_f32_dpp %3, %3, %3 row_shr:1 row_mask:0xf bank_mask:0xf\n\t"   \
        "v_add_f32_dpp %4, %4, %4 row_shr:1 row_mask:0xf bank_mask:0xf\n\t"   \
        "v_add_f32_dpp %5, %5, %5 row_shr:1 row_mask:0xf bank_mask:0xf\n\t"   \
        "v_add_f32_dpp %6, %6, %6 row_shr:1 row_mask:0xf bank_mask:0xf\n\t"   \
        "v_add_f32_dpp %0, %0, %0 row_shr:2 row_mask:0xf bank_mask:0xf\n\t"   \
        "v_add_f32_dpp %1, %1, %1 row_shr:2 row_mask:0xf bank_mask:0xf\n\t"   \
        "v_add_f32_dpp %2, %2, %2 row_shr:2 row_mask:0xf bank_mask:0xf\n\t"   \
        "v_add_f32_dpp %3, %3, %3 row_shr:2 row_mask:0xf bank_mask:0xf\n\t"   \
        "v_add_f32_dpp %4, %4, %4 row_shr:2 row_mask:0xf bank_mask:0xf\n\t"   \
        "v_add_f32_dpp %5, %5, %5 row_shr:2 row_mask:0xf bank_mask:0xf\n\t"   \
        "v_add_f32_dpp %6, %6, %6 row_shr:2 row_mask:0xf bank_mask:0xf\n\t"   \
        "v_add_f32_dpp %0, %0, %0 row_shr:4 row_mask:0xf bank_mask:0xf\n\t"   \
        "v_add_f32_dpp %1, %1, %1 row_shr:4 row_mask:0xf bank_mask:0xf\n\t"   \
        "v_add_f32_dpp %2, %2, %2 row_shr:4 row_mask:0xf bank_mask:0xf\n\t"   \
        "v_add_f32_dpp %3, %3, %3 row_shr:4 row_mask:0xf bank_mask:0xf\n\t"   \
        "v_add_f32_dpp %4, %4, %4 row_shr:4 row_mask:0xf bank_mask:0xf\n\t"   \
        "v_add_f32_dpp %5, %5, %5 row_shr:4 row_mask:0xf bank_mask:0xf\n\t"   \
        "v_add_f32_dpp %6, %6, %6 row_shr:4 row_mask:0xf bank_mask:0xf\n\t"   \
        "v_add_f32_dpp %0, %0, %0 row_shr:8 row_mask:0xf bank_mask:0xf\n\t"   \
        "v_add_f32_dpp %1, %1, %1 row_shr:8 row_mask:0xf bank_mask:0xf\n\t"   \
        "v_add_f32_dpp %2, %2, %2 row_shr:8 row_mask:0xf bank_mask:0xf\n\t"   \
        "v_add_f32_dpp %3, %3, %3 row_shr:8 row_mask:0xf bank_mask:0xf\n\t"   \
        "v_add_f32_dpp %4, %4, %4 row_shr:8 row_mask:0xf bank_mask:0xf\n\t"   \
        "v_add_f32_dpp %5, %5, %5 row_shr:8 row_mask:0xf bank_mask:0xf\n\t"   \
        "v_add_f32_dpp %6, %6, %6 row_shr:8 row_mask:0xf bank_mask:0xf\n\t"   \
        "v_add_f32_dpp %0, %0, %0 row_bcast:15 row_mask:0xa bank_mask:0xf\n\t"\
        "v_add_f32_dpp %1, %1, %1 row_bcast:15 row_mask:0xa bank_mask:0xf\n\t"\
        "v_add_f32_dpp %2, %2, %2 row_bcast:15 row_mask:0xa bank_mask:0xf\n\t"\
        "v_add_f32_dpp %3, %3, %3 row_bcast:15 row_mask:0xa bank_mask:0xf\n\t"\
        "v_add_f32_dpp %4, %4, %4 row_bcast:15 row_mask:0xa bank_mask:0xf\n\t"\
        "v_add_f32_dpp %5, %5, %5 row_bcast:15 row_mask:0xa bank_mask:0xf\n\t"\
        "v_add_f32_dpp %6, %6, %6 row_bcast:15 row_mask:0xa bank_mask:0xf\n\t"\
        "v_add_f32_dpp %0, %0, %0 row_bcast:31 row_mask:0xc bank_mask:0xf\n\t"\
        "v_add_f32_dpp %1, %1, %1 row_bcast:31 row_mask:0xc bank_mask:0xf\n\t"\
        "v_add_f32_dpp %2, %2, %2 row_bcast:31 row_mask:0xc bank_mask:0xf\n\t"\
        "v_add_f32_dpp %3, %3, %3 row_bcast:31 row_mask:0xc bank_mask:0xf\n\t"\
        "v_add_f32_dpp %4, %4, %4 row_bcast:31 row_mask:0xc bank_mask:0xf\n\t"\
        "v_add_f32_dpp %5, %5, %5 row_bcast:31 row_mask:0xc bank_mask:0xf\n\t"\
        "v_add_f32_dpp %6, %6, %6 row_bcast:31 row_mask:0xc bank_mask:0xf\n\t"\
        "v_readlane_b32 %7, %0, 63\n\t"                                       \
        "v_readlane_b32 %8, %1, 63\n\t"                                       \
        "v_readlane_b32 %9, %2, 63\n\t"                                       \
        "v_readlane_b32 %10, %3, 63\n\t"                                      \
        "v_readlane_b32 %11, %4, 63\n\t"                                      \
        "v_readlane_b32 %12, %5, 63\n\t"                                      \
        "v_readlane_b32 %13, %6, 63\n\t"                                      \
        "s_nop 1"                                                             \
        : "+v"(e0), "+v"(e1), "+v"(e2), "+v"(e3),                             \
          "+v"(e4), "+v"(e5), "+v"(e6),                                       \
          "=s"(s0_), "=s"(s1_), "=s"(s2_), "=s"(s3_),                         \
          "=s"(s4_), "=s"(s5_), "=s"(s6_))

__global__ __launch_bounds__(64) void sinkhorn_kernel(
    const float* __restrict__ theta,  // [64,7]
    const float* __restrict__ phi,    // [7]
    const float* __restrict__ n,      // [64]
    const float* __restrict__ sens,   // [64]
    const float* __restrict__ err,    // [7]
    float* __restrict__ out)          // [64,7]
{
    const int lane = threadIdx.x;     // one wave: lane == row

    const float ni = n[lane];
    const float si = sens[lane];

    // Base-2 domain. K2 = (theta - C)*log2e/EPS.
    const float kscale = LOG2E_ / EPS_;
    float K2[NB];
    #pragma unroll
    for (int j = 0; j < NB; ++j)
        K2[j] = (theta[lane * NB + j] - ni * si * err[j]) * kscale;

    const float nsum   = wave_sum_bcast(ni);
    const float aT     = ni / nsum + TINY_;
    const float log_a2 = log2_hw(aT);

    // log_b2 = log2(softmax(phi) + TINY)  (uniform; per lane)
    float t2v[NB];
    #pragma unroll
    for (int j = 0; j < NB; ++j) t2v[j] = phi[j] * LOG2E_;
    float pmax = t2v[0];
    #pragma unroll
    for (int j = 1; j < NB; ++j) pmax = fmaxf(pmax, t2v[j]);
    float psum = 0.f;
    #pragma unroll
    for (int j = 0; j < NB; ++j) psum += exp2_hw(t2v[j] - pmax);
    const float lps = log2_hw(psum);
    float bT[NB], log_b2[NB], cb[NB];
    #pragma unroll
    for (int j = 0; j < NB; ++j) {
        bT[j]     = exp2_hw(t2v[j] - pmax - lps) + TINY_;
        log_b2[j] = log2_hw(bT[j]);
        cb[j]     = log_b2[j] - log_a2;
    }

    // ---- Phase 1: log-domain (exact R8 body), 120 iterations ----
    float t[NB];
    #pragma unroll
    for (int j = 0; j < NB; ++j) t[j] = K2[j] - log_b2[j];

    const float LOF = __int_as_float(0x0D800000);  // 2^-100
    const float HIF = __int_as_float(0x71800000);  // 2^+100
    const unsigned LO = 0x0D800000u, HI = 0x71800000u;

    for (int it = 0; it < ITERS1_; ++it) {
        float a0 = t[0] + cb[0], a1 = t[1] + cb[1], a2 = t[2] + cb[2],
              a3 = t[3] + cb[3], a4 = t[4] + cb[4], a5 = t[5] + cb[5],
              a6 = t[6] + cb[6];
        float s = ((exp2_hw(a0) + exp2_hw(a1)) + (exp2_hw(a2) + exp2_hw(a3)))
                + ((exp2_hw(a4) + exp2_hw(a5)) + exp2_hw(a6));
        float L;
        const bool ok = (s >= LOF) && (s <= HIF);   // NaN/inf -> false
        if (__ballot(ok) == ~0ull) {
            L = log2_hw(s);
        } else {
            float m = fmaxf(fmaxf(fmaxf(a0, a1), fmaxf(a2, a3)),
                            fmaxf(fmaxf(a4, a5), a6));
            float s2 = ((exp2_hw(a0 - m) + exp2_hw(a1 - m))
                      + (exp2_hw(a2 - m) + exp2_hw(a3 - m)))
                     + ((exp2_hw(a4 - m) + exp2_hw(a5 - m)) + exp2_hw(a6 - m));
            L = m + log2_hw(s2);
        }

        float q0 = t[0] - L, q1 = t[1] - L, q2 = t[2] - L, q3 = t[3] - L,
              q4 = t[4] - L, q5 = t[5] - L, q6 = t[6] - L;
        float e0 = exp2_hw(q0), e1 = exp2_hw(q1), e2 = exp2_hw(q2),
              e3 = exp2_hw(q3), e4 = exp2_hw(q4), e5 = exp2_hw(q5),
              e6 = exp2_hw(q6);
        float ss0, ss1, ss2, ss3, ss4, ss5, ss6;
        WAVE_SUM7(e0, e1, e2, e3, e4, e5, e6, ss0, ss1, ss2, ss3, ss4, ss5, ss6);

        const unsigned u0 = __float_as_uint(ss0), u1 = __float_as_uint(ss1),
                       u2 = __float_as_uint(ss2), u3 = __float_as_uint(ss3),
                       u4 = __float_as_uint(ss4), u5 = __float_as_uint(ss5),
                       u6 = __float_as_uint(ss6);
        const unsigned umin = min(min(min(u0, u1), min(u2, u3)),
                                  min(min(u4, u5), u6));
        const unsigned umax = max(max(max(u0, u1), max(u2, u3)),
                                  max(max(u4, u5), u6));
        if (umin < LO || umax > HI) {
            float M0, M1, M2, M3, M4, M5, M6;
            WAVE_MAX7(q0, q1, q2, q3, q4, q5, q6, M0, M1, M2, M3, M4, M5, M6);
            e0 = exp2_hw(q0 - M0); e1 = exp2_hw(q1 - M1);
            e2 = exp2_hw(q2 - M2); e3 = exp2_hw(q3 - M3);
            e4 = exp2_hw(q4 - M4); e5 = exp2_hw(q5 - M5);
            e6 = exp2_hw(q6 - M6);
            WAVE_SUM7(e0, e1, e2, e3, e4, e5, e6, ss0, ss1, ss2, ss3, ss4, ss5, ss6);
            t[0] = q0 - (M0 + log2_hw(ss0)); t[1] = q1 - (M1 + log2_hw(ss1));
            t[2] = q2 - (M2 + log2_hw(ss2)); t[3] = q3 - (M3 + log2_hw(ss3));
            t[4] = q4 - (M4 + log2_hw(ss4)); t[5] = q5 - (M5 + log2_hw(ss5));
            t[6] = q6 - (M6 + log2_hw(ss6));
        } else {
            t[0] = q0 - log2_hw(ss0); t[1] = q1 - log2_hw(ss1);
            t[2] = q2 - log2_hw(ss2); t[3] = q3 - log2_hw(ss3);
            t[4] = q4 - log2_hw(ss4); t[5] = q5 - log2_hw(ss5);
            t[6] = q6 - log2_hw(ss6);
        }
    }

    // ---- Switch: U = 2^t, B = 2^cb. Entries with t < -126 flush to 0/denorm;
    // by the residual bound they can never matter again (need +105 log2 climb,
    // remaining movement <= ~53). ----
    float U[NB], B[NB];
    #pragma unroll
    for (int j = 0; j < NB; ++j) {
        U[j] = exp2_hw(t[j]);
        B[j] = exp2_hw(cb[j]);
    }

    const float SSMIN = 1e-37f;  // backstop (ss >= ~2^-21 analytically)

    // ---- Phase 2: multiplicative (R11 body), 80 iterations ----
    for (int it = 0; it < ITERS2_; ++it) {
        float p0 = U[0] * B[0], p1 = U[1] * B[1], p2 = U[2] * B[2],
              p3 = U[3] * B[3], p4 = U[4] * B[4], p5 = U[5] * B[5],
              p6 = U[6] * B[6];
        const float s = ((p0 + p1) + (p2 + p3)) + ((p4 + p5) + p6);
        const float rs = rcp_hw(s);
        float w0 = U[0] * rs, w1 = U[1] * rs, w2 = U[2] * rs,
              w3 = U[3] * rs, w4 = U[4] * rs, w5 = U[5] * rs,
              w6 = U[6] * rs;

        float c0 = w0, c1 = w1, c2 = w2, c3 = w3, c4 = w4, c5 = w5, c6 = w6;
        float ss0, ss1, ss2, ss3, ss4, ss5, ss6;
        WAVE_SUM7(c0, c1, c2, c3, c4, c5, c6, ss0, ss1, ss2, ss3, ss4, ss5, ss6);

        const float r0 = rcp_hw(fmaxf(ss0, SSMIN));
        const float r1 = rcp_hw(fmaxf(ss1, SSMIN));
        const float r2 = rcp_hw(fmaxf(ss2, SSMIN));
        const float r3 = rcp_hw(fmaxf(ss3, SSMIN));
        const float r4 = rcp_hw(fmaxf(ss4, SSMIN));
        const float r5 = rcp_hw(fmaxf(ss5, SSMIN));
        const float r6 = rcp_hw(fmaxf(ss6, SSMIN));
        U[0] = w0 * r0; U[1] = w1 * r1; U[2] = w2 * r2; U[3] = w3 * r3;
        U[4] = w4 * r4; U[5] = w5 * r5; U[6] = w6 * r6;
    }

    // ---- Epilogue: P = U * bT; normalize by total (+TINY) ----
    float pr[NB];
    float rowsum = 0.f;
    #pragma unroll
    for (int j = 0; j < NB; ++j) {
        pr[j] = U[j] * bT[j];
        rowsum += pr[j];
    }
    const float total = wave_sum_bcast(rowsum);   // ~1 at convergence
    const float inv = 1.0f / (total + TINY_);
    #pragma unroll
    for (int j = 0; j < NB; ++j)
        out[lane * NB + j] = pr[j] * inv;
}

extern "C" void kernel_launch(void* const* d_in, const int* in_sizes, int n_in,
                              void* d_out, int out_size, void* d_ws, size_t ws_size,
                              hipStream_t stream) {
    const float* theta = (const float*)d_in[0];
    const float* phi   = (const float*)d_in[1];
    const float* n     = (const float*)d_in[2];
    const float* sens  = (const float*)d_in[3];
    const float* err   = (const float*)d_in[4];
    float* out = (float*)d_out;

    sinkhorn_kernel<<<1, 64, 0, stream>>>(theta, phi, n, sens, err, out);
}

// Round 15
// 115.124 us; speedup vs baseline: 1.1767x; 1.0213x over previous
//
#include <hip/hip_runtime.h>
#include <math.h>

#define NB 7
#define EPS_ 0.02f
#define ITERS1_ 120   // log-domain phase (handles +-25k log2 transient exactly)
#define ITERS2_ 80    // multiplicative phase; total 200 == reference count.
// R12/R14 calibration: reference@200 is NOT converged (P still moves
// ~7e-4/iter at iter 200). Trajectory matching at exactly 200 iterations is
// mandatory; truncation and early exit are dead. Switch@120 validated in R13
// (absmax bit-identical to the pure log-domain R8 kernel).
#define TINY_ 1e-40f
#define LOG2E_ 1.4426950408889634f
#define LN2_   0.6931471805599453f

// Bare hardware transcendentals (base-2 domain).
__device__ __forceinline__ float exp2_hw(float x) {
#if __has_builtin(__builtin_amdgcn_exp2f)
    return __builtin_amdgcn_exp2f(x);
#else
    return __expf(x * LN2_);
#endif
}
__device__ __forceinline__ float log2_hw(float x) {
#if __has_builtin(__builtin_amdgcn_logf)
    return __builtin_amdgcn_logf(x);
#else
    return __logf(x) * LOG2E_;
#endif
}
__device__ __forceinline__ float rcp_hw(float x) {
#if __has_builtin(__builtin_amdgcn_rcpf)
    return __builtin_amdgcn_rcpf(x);
#else
    return 1.0f / x;
#endif
}

// ---- DPP helpers ----
template <int CTRL>
__device__ __forceinline__ float dpp_ident(float identity, float x) {
    return __int_as_float(__builtin_amdgcn_update_dpp(
        __float_as_int(identity), __float_as_int(x), CTRL, 0xF, 0xF, false));
}
__device__ __forceinline__ float readlane63(float x) {
    return __int_as_float(__builtin_amdgcn_readlane(__float_as_int(x), 63));
}
__device__ __forceinline__ float wave_sum_bcast(float s) {
    s += dpp_ident<0x111>(0.f, s);
    s += dpp_ident<0x112>(0.f, s);
    s += dpp_ident<0x114>(0.f, s);
    s += dpp_ident<0x118>(0.f, s);
    s += dpp_ident<0x142>(0.f, s);
    s += dpp_ident<0x143>(0.f, s);
    return readlane63(s);
}
__device__ __forceinline__ float wave_max_bcast(float m) {
    const float NI = __int_as_float(0xff800000);
    m = fmaxf(m, dpp_ident<0x111>(NI, m));
    m = fmaxf(m, dpp_ident<0x112>(NI, m));
    m = fmaxf(m, dpp_ident<0x114>(NI, m));
    m = fmaxf(m, dpp_ident<0x118>(NI, m));
    m = fmaxf(m, dpp_ident<0x142>(NI, m));
    m = fmaxf(m, dpp_ident<0x143>(NI, m));
    return readlane63(m);
}

// 7-column interleaved 64-lane MAX reduce (keep-old DPP = identity-free).
#define WAVE_MAX7(v0,v1,v2,v3,v4,v5,v6, m0,m1,m2,m3,m4,m5,m6)                 \
  {                                                                           \
    float r0,r1,r2,r3,r4,r5,r6;                                               \
    asm("v_mov_b32 %0, %14\n\t"                                               \
        "v_mov_b32 %1, %15\n\t"                                               \
        "v_mov_b32 %2, %16\n\t"                                               \
        "v_mov_b32 %3, %17\n\t"                                               \
        "v_mov_b32 %4, %18\n\t"                                               \
        "v_mov_b32 %5, %19\n\t"                                               \
        "v_mov_b32 %6, %20\n\t"                                               \
        "v_max_f32_dpp %0, %0, %0 row_shr:1 row_mask:0xf bank_mask:0xf\n\t"   \
        "v_max_f32_dpp %1, %1, %1 row_shr:1 row_mask:0xf bank_mask:0xf\n\t"   \
        "v_max_f32_dpp %2, %2, %2 row_shr:1 row_mask:0xf bank_mask:0xf\n\t"   \
        "v_max_f32_dpp %3, %3, %3 row_shr:1 row_mask:0xf bank_mask:0xf\n\t"   \
        "v_max_f32_dpp %4, %4, %4 row_shr:1 row_mask:0xf bank_mask:0xf\n\t"   \
        "v_max_f32_dpp %5, %5, %5 row_shr:1 row_mask:0xf bank_mask:0xf\n\t"   \
        "v_max_f32_dpp %6, %6, %6 row_shr:1 row_mask:0xf bank_mask:0xf\n\t"   \
        "v_max_f32_dpp %0, %0, %0 row_shr:2 row_mask:0xf bank_mask:0xf\n\t"   \
        "v_max_f32_dpp %1, %1, %1 row_shr:2 row_mask:0xf bank_mask:0xf\n\t"   \
        "v_max_f32_dpp %2, %2, %2 row_shr:2 row_mask:0xf bank_mask:0xf\n\t"   \
        "v_max_f32_dpp %3, %3, %3 row_shr:2 row_mask:0xf bank_mask:0xf\n\t"   \
        "v_max_f32_dpp %4, %4, %4 row_shr:2 row_mask:0xf bank_mask:0xf\n\t"   \
        "v_max_f32_dpp %5, %5, %5 row_shr:2 row_mask:0xf bank_mask:0xf\n\t"   \
        "v_max_f32_dpp %6, %6, %6 row_shr:2 row_mask:0xf bank_mask:0xf\n\t"   \
        "v_max_f32_dpp %0, %0, %0 row_shr:4 row_mask:0xf bank_mask:0xf\n\t"   \
        "v_max_f32_dpp %1, %1, %1 row_shr:4 row_mask:0xf bank_mask:0xf\n\t"   \
        "v_max_f32_dpp %2, %2, %2 row_shr:4 row_mask:0xf bank_mask:0xf\n\t"   \
        "v_max_f32_dpp %3, %3, %3 row_shr:4 row_mask:0xf bank_mask:0xf\n\t"   \
        "v_max_f32_dpp %4, %4, %4 row_shr:4 row_mask:0xf bank_mask:0xf\n\t"   \
        "v_max_f32_dpp %5, %5, %5 row_shr:4 row_mask:0xf bank_mask:0xf\n\t"   \
        "v_max_f32_dpp %6, %6, %6 row_shr:4 row_mask:0xf bank_mask:0xf\n\t"   \
        "v_max_f32_dpp %0, %0, %0 row_shr:8 row_mask:0xf bank_mask:0xf\n\t"   \
        "v_max_f32_dpp %1, %1, %1 row_shr:8 row_mask:0xf bank_mask:0xf\n\t"   \
        "v_max_f32_dpp %2, %2, %2 row_shr:8 row_mask:0xf bank_mask:0xf\n\t"   \
        "v_max_f32_dpp %3, %3, %3 row_shr:8 row_mask:0xf bank_mask:0xf\n\t"   \
        "v_max_f32_dpp %4, %4, %4 row_shr:8 row_mask:0xf bank_mask:0xf\n\t"   \
        "v_max_f32_dpp %5, %5, %5 row_shr:8 row_mask:0xf bank_mask:0xf\n\t"   \
        "v_max_f32_dpp %6, %6, %6 row_shr:8 row_mask:0xf bank_mask:0xf\n\t"   \
        "v_max_f32_dpp %0, %0, %0 row_bcast:15 row_mask:0xa bank_mask:0xf\n\t"\
        "v_max_f32_dpp %1, %1, %1 row_bcast:15 row_mask:0xa bank_mask:0xf\n\t"\
        "v_max_f32_dpp %2, %2, %2 row_bcast:15 row_mask:0xa bank_mask:0xf\n\t"\
        "v_max_f32_dpp %3, %3, %3 row_bcast:15 row_mask:0xa bank_mask:0xf\n\t"\
        "v_max_f32_dpp %4, %4, %4 row_bcast:15 row_mask:0xa bank_mask:0xf\n\t"\
        "v_max_f32_dpp %5, %5, %5 row_bcast:15 row_mask:0xa bank_mask:0xf\n\t"\
        "v_max_f32_dpp %6, %6, %6 row_bcast:15 row_mask:0xa bank_mask:0xf\n\t"\
        "v_max_f32_dpp %0, %0, %0 row_bcast:31 row_mask:0xc bank_mask:0xf\n\t"\
        "v_max_f32_dpp %1, %1, %1 row_bcast:31 row_mask:0xc bank_mask:0xf\n\t"\
        "v_max_f32_dpp %2, %2, %2 row_bcast:31 row_mask:0xc bank_mask:0xf\n\t"\
        "v_max_f32_dpp %3, %3, %3 row_bcast:31 row_mask:0xc bank_mask:0xf\n\t"\
        "v_max_f32_dpp %4, %4, %4 row_bcast:31 row_mask:0xc bank_mask:0xf\n\t"\
        "v_max_f32_dpp %5, %5, %5 row_bcast:31 row_mask:0xc bank_mask:0xf\n\t"\
        "v_max_f32_dpp %6, %6, %6 row_bcast:31 row_mask:0xc bank_mask:0xf\n\t"\
        "v_readlane_b32 %7, %0, 63\n\t"                                       \
        "v_readlane_b32 %8, %1, 63\n\t"                                       \
        "v_readlane_b32 %9, %2, 63\n\t"                                       \
        "v_readlane_b32 %10, %3, 63\n\t"                                      \
        "v_readlane_b32 %11, %4, 63\n\t"                                      \
        "v_readlane_b32 %12, %5, 63\n\t"                                      \
        "v_readlane_b32 %13, %6, 63\n\t"                                      \
        "s_nop 1"                                                             \
        : "=&v"(r0), "=&v"(r1), "=&v"(r2), "=&v"(r3),                         \
          "=&v"(r4), "=&v"(r5), "=&v"(r6),                                    \
          "=s"(m0), "=s"(m1), "=s"(m2), "=s"(m3),                             \
          "=s"(m4), "=s"(m5), "=s"(m6)                                        \
        : "v"(v0), "v"(v1), "v"(v2), "v"(v3), "v"(v4), "v"(v5), "v"(v6));     \
  }

// 7-column interleaved 64-lane SUM reduce; e0..e6 clobbered; sums -> SGPRs.
#define WAVE_SUM7(e0,e1,e2,e3,e4,e5,e6, s0_,s1_,s2_,s3_,s4_,s5_,s6_)          \
    asm("s_nop 1\n\t"                                                         \
        "v_add_f32_dpp %0, %0, %0 row_shr:1 row_mask:0xf bank_mask:0xf\n\t"   \
        "v_add_f32_dpp %1, %1, %1 row_shr:1 row_mask:0xf bank_mask:0xf\n\t"   \
        "v_add_f32_dpp %2, %2, %2 row_shr:1 row_mask:0xf bank_mask:0xf\n\t"   \
        "v_add_f32_dpp %3, %3, %3 row_shr:1 row_mask:0xf bank_mask:0xf\n\t"   \
        "v_add_f32_dpp %4, %4, %4 row_shr:1 row_mask:0xf bank_mask:0xf\n\t"   \
        "v_add_f32_dpp %5, %5, %5 row_shr:1 row_mask:0xf bank_mask:0xf\n\t"   \
        "v_add_f32_dpp %6, %6, %6 row_shr:1 row_mask:0xf bank_mask:0xf\n\t"   \
        "v_add_f32_dpp %0, %0, %0 row_shr:2 row_mask:0xf bank_mask:0xf\n\t"   \
        "v_add_f32_dpp %1, %1, %1 row_shr:2 row_mask:0xf bank_mask:0xf\n\t"   \
        "v_add_f32_dpp %2, %2, %2 row_shr:2 row_mask:0xf bank_mask:0xf\n\t"   \
        "v_add_f32_dpp %3, %3, %3 row_shr:2 row_mask:0xf bank_mask:0xf\n\t"   \
        "v_add_f32_dpp %4, %4, %4 row_shr:2 row_mask:0xf bank_mask:0xf\n\t"   \
        "v_add_f32_dpp %5, %5, %5 row_shr:2 row_mask:0xf bank_mask:0xf\n\t"   \
        "v_add_f32_dpp %6, %6, %6 row_shr:2 row_mask:0xf bank_mask:0xf\n\t"   \
        "v_add_f32_dpp %0, %0, %0 row_shr:4 row_mask:0xf bank_mask:0xf\n\t"   \
        "v_add_f32_dpp %1, %1, %1 row_shr:4 row_mask:0xf bank_mask:0xf\n\t"   \
        "v_add_f32_dpp %2, %2, %2 row_shr:4 row_mask:0xf bank_mask:0xf\n\t"   \
        "v_add_f32_dpp %3, %3, %3 row_shr:4 row_mask:0xf bank_mask:0xf\n\t"   \
        "v_add_f32_dpp %4, %4, %4 row_shr:4 row_mask:0xf bank_mask:0xf\n\t"   \
        "v_add_f32_dpp %5, %5, %5 row_shr:4 row_mask:0xf bank_mask:0xf\n\t"   \
        "v_add_f32_dpp %6, %6, %6 row_shr:4 row_mask:0xf bank_mask:0xf\n\t"   \
        "v_add_f32_dpp %0, %0, %0 row_shr:8 row_mask:0xf bank_mask:0xf\n\t"   \
        "v_add_f32_dpp %1, %1, %1 row_shr:8 row_mask:0xf bank_mask:0xf\n\t"   \
        "v_add_f32_dpp %2, %2, %2 row_shr:8 row_mask:0xf bank_mask:0xf\n\t"   \
        "v_add_f32_dpp %3, %3, %3 row_shr:8 row_mask:0xf bank_mask:0xf\n\t"   \
        "v_add_f32_dpp %4, %4, %4 row_shr:8 row_mask:0xf bank_mask:0xf\n\t"   \
        "v_add_f32_dpp %5, %5, %5 row_shr:8 row_mask:0xf bank_mask:0xf\n\t"   \
        "v_add_f32_dpp %6, %6, %6 row_shr:8 row_mask:0xf bank_mask:0xf\n\t"   \
        "v_add_f32_dpp %0, %0, %0 row_bcast:15 row_mask:0xa bank_mask:0xf\n\t"\
        "v_add_f32_dpp %1, %1, %1 row_bcast:15 row_mask:0xa bank_mask:0xf\n\t"\
        "v_add_f32_dpp %2, %2, %2 row_bcast:15 row_mask:0xa bank_mask:0xf\n\t"\
        "v_add_f32_dpp %3, %3, %3 row_bcast:15 row_mask:0xa bank_mask:0xf\n\t"\
        "v_add_f32_dpp %4, %4, %4 row_bcast:15 row_mask:0xa bank_mask:0xf\n\t"\
        "v_add_f32_dpp %5, %5, %5 row_bcast:15 row_mask:0xa bank_mask:0xf\n\t"\
        "v_add_f32_dpp %6, %6, %6 row_bcast:15 row_mask:0xa bank_mask:0xf\n\t"\
        "v_add_f32_dpp %0, %0, %0 row_bcast:31 row_mask:0xc bank_mask:0xf\n\t"\
        "v_add_f32_dpp %1, %1, %1 row_bcast:31 row_mask:0xc bank_mask:0xf\n\t"\
        "v_add_f32_dpp %2, %2, %2 row_bcast:31 row_mask:0xc bank_mask:0xf\n\t"\
        "v_add_f32_dpp %3, %3, %3 row_bcast:31 row_mask:0xc bank_mask:0xf\n\t"\
        "v_add_f32_dpp %4, %4, %4 row_bcast:31 row_mask:0xc bank_mask:0xf\n\t"\
        "v_add_f32_dpp %5, %5, %5 row_bcast:31 row_mask:0xc bank_mask:0xf\n\t"\
        "v_add_f32_dpp %6, %6, %6 row_bcast:31 row_mask:0xc bank_mask:0xf\n\t"\
        "v_readlane_b32 %7, %0, 63\n\t"                                       \
        "v_readlane_b32 %8, %1, 63\n\t"                                       \
        "v_readlane_b32 %9, %2, 63\n\t"                                       \
        "v_readlane_b32 %10, %3, 63\n\t"                                      \
        "v_readlane_b32 %11, %4, 63\n\t"                                      \
        "v_readlane_b32 %12, %5, 63\n\t"                                      \
        "v_readlane_b32 %13, %6, 63\n\t"                                      \
        "s_nop 1"                                                             \
        : "+v"(e0), "+v"(e1), "+v"(e2), "+v"(e3),                             \
          "+v"(e4), "+v"(e5), "+v"(e6),                                       \
          "=s"(s0_), "=s"(s1_), "=s"(s2_), "=s"(s3_),                         \
          "=s"(s4_), "=s"(s5_), "=s"(s6_))

__global__ __launch_bounds__(64) void sinkhorn_kernel(
    const float* __restrict__ theta,  // [64,7]
    const float* __restrict__ phi,    // [7]
    const float* __restrict__ n,      // [64]
    const float* __restrict__ sens,   // [64]
    const float* __restrict__ err,    // [7]
    float* __restrict__ out)          // [64,7]
{
    const int lane = threadIdx.x;     // one wave: lane == row

    const float ni = n[lane];
    const float si = sens[lane];

    // Base-2 domain. K2 = (theta - C)*log2e/EPS.
    const float kscale = LOG2E_ / EPS_;
    float K2[NB];
    #pragma unroll
    for (int j = 0; j < NB; ++j)
        K2[j] = (theta[lane * NB + j] - ni * si * err[j]) * kscale;

    const float nsum   = wave_sum_bcast(ni);
    const float aT     = ni / nsum + TINY_;
    const float log_a2 = log2_hw(aT);

    // log_b2 = log2(softmax(phi) + TINY)  (uniform; per lane)
    float t2v[NB];
    #pragma unroll
    for (int j = 0; j < NB; ++j) t2v[j] = phi[j] * LOG2E_;
    float pmax = t2v[0];
    #pragma unroll
    for (int j = 1; j < NB; ++j) pmax = fmaxf(pmax, t2v[j]);
    float psum = 0.f;
    #pragma unroll
    for (int j = 0; j < NB; ++j) psum += exp2_hw(t2v[j] - pmax);
    const float lps = log2_hw(psum);
    float bT[NB], log_b2[NB], cb[NB];
    #pragma unroll
    for (int j = 0; j < NB; ++j) {
        bT[j]     = exp2_hw(t2v[j] - pmax - lps) + TINY_;
        log_b2[j] = log2_hw(bT[j]);
        cb[j]     = log_b2[j] - log_a2;
    }

    // ---- Phase 1: log-domain (R8 body), 120 iterations ----
    float t[NB];
    #pragma unroll
    for (int j = 0; j < NB; ++j) t[j] = K2[j] - log_b2[j];

    const float LOF = __int_as_float(0x0D800000);  // 2^-100
    const float HIF = __int_as_float(0x71800000);  // 2^+100
    const unsigned LO = 0x0D800000u, HI = 0x71800000u;

    for (int it = 0; it < ITERS1_; ++it) {
        float a0 = t[0] + cb[0], a1 = t[1] + cb[1], a2 = t[2] + cb[2],
              a3 = t[3] + cb[3], a4 = t[4] + cb[4], a5 = t[5] + cb[5],
              a6 = t[6] + cb[6];
        float s = ((exp2_hw(a0) + exp2_hw(a1)) + (exp2_hw(a2) + exp2_hw(a3)))
                + ((exp2_hw(a4) + exp2_hw(a5)) + exp2_hw(a6));
        float L;
        const bool ok = (s >= LOF) && (s <= HIF);   // NaN/inf -> false
        if (__ballot(ok) == ~0ull) {
            L = log2_hw(s);
        } else {
            float m = fmaxf(fmaxf(fmaxf(a0, a1), fmaxf(a2, a3)),
                            fmaxf(fmaxf(a4, a5), a6));
            float s2 = ((exp2_hw(a0 - m) + exp2_hw(a1 - m))
                      + (exp2_hw(a2 - m) + exp2_hw(a3 - m)))
                     + ((exp2_hw(a4 - m) + exp2_hw(a5 - m)) + exp2_hw(a6 - m));
            L = m + log2_hw(s2);
        }

        float q0 = t[0] - L, q1 = t[1] - L, q2 = t[2] - L, q3 = t[3] - L,
              q4 = t[4] - L, q5 = t[5] - L, q6 = t[6] - L;
        float e0 = exp2_hw(q0), e1 = exp2_hw(q1), e2 = exp2_hw(q2),
              e3 = exp2_hw(q3), e4 = exp2_hw(q4), e5 = exp2_hw(q5),
              e6 = exp2_hw(q6);
        float ss0, ss1, ss2, ss3, ss4, ss5, ss6;
        WAVE_SUM7(e0, e1, e2, e3, e4, e5, e6, ss0, ss1, ss2, ss3, ss4, ss5, ss6);

        const unsigned u0 = __float_as_uint(ss0), u1 = __float_as_uint(ss1),
                       u2 = __float_as_uint(ss2), u3 = __float_as_uint(ss3),
                       u4 = __float_as_uint(ss4), u5 = __float_as_uint(ss5),
                       u6 = __float_as_uint(ss6);
        const unsigned umin = min(min(min(u0, u1), min(u2, u3)),
                                  min(min(u4, u5), u6));
        const unsigned umax = max(max(max(u0, u1), max(u2, u3)),
                                  max(max(u4, u5), u6));
        if (umin < LO || umax > HI) {
            float M0, M1, M2, M3, M4, M5, M6;
            WAVE_MAX7(q0, q1, q2, q3, q4, q5, q6, M0, M1, M2, M3, M4, M5, M6);
            e0 = exp2_hw(q0 - M0); e1 = exp2_hw(q1 - M1);
            e2 = exp2_hw(q2 - M2); e3 = exp2_hw(q3 - M3);
            e4 = exp2_hw(q4 - M4); e5 = exp2_hw(q5 - M5);
            e6 = exp2_hw(q6 - M6);
            WAVE_SUM7(e0, e1, e2, e3, e4, e5, e6, ss0, ss1, ss2, ss3, ss4, ss5, ss6);
            t[0] = q0 - (M0 + log2_hw(ss0)); t[1] = q1 - (M1 + log2_hw(ss1));
            t[2] = q2 - (M2 + log2_hw(ss2)); t[3] = q3 - (M3 + log2_hw(ss3));
            t[4] = q4 - (M4 + log2_hw(ss4)); t[5] = q5 - (M5 + log2_hw(ss5));
            t[6] = q6 - (M6 + log2_hw(ss6));
        } else {
            t[0] = q0 - log2_hw(ss0); t[1] = q1 - log2_hw(ss1);
            t[2] = q2 - log2_hw(ss2); t[3] = q3 - log2_hw(ss3);
            t[4] = q4 - log2_hw(ss4); t[5] = q5 - log2_hw(ss5);
            t[6] = q6 - log2_hw(ss6);
        }
    }

    // ---- Switch: U = 2^t, B = 2^cb (validated @120 in R13: trajectory
    // bit-identical to pure log-domain run). ----
    float U[NB], B[NB];
    #pragma unroll
    for (int j = 0; j < NB; ++j) {
        U[j] = exp2_hw(t[j]);
        B[j] = exp2_hw(cb[j]);
    }

    // ---- Phase 2: multiplicative, 80 iterations. SSMIN clamps removed:
    // in R13 they never activated (absmax bit-identical to R8), so the
    // rcp operates on the same ss values either way. ----
    for (int it = 0; it < ITERS2_; ++it) {
        float p0 = U[0] * B[0], p1 = U[1] * B[1], p2 = U[2] * B[2],
              p3 = U[3] * B[3], p4 = U[4] * B[4], p5 = U[5] * B[5],
              p6 = U[6] * B[6];
        const float s = ((p0 + p1) + (p2 + p3)) + ((p4 + p5) + p6);
        const float rs = rcp_hw(s);
        float w0 = U[0] * rs, w1 = U[1] * rs, w2 = U[2] * rs,
              w3 = U[3] * rs, w4 = U[4] * rs, w5 = U[5] * rs,
              w6 = U[6] * rs;

        float c0 = w0, c1 = w1, c2 = w2, c3 = w3, c4 = w4, c5 = w5, c6 = w6;
        float ss0, ss1, ss2, ss3, ss4, ss5, ss6;
        WAVE_SUM7(c0, c1, c2, c3, c4, c5, c6, ss0, ss1, ss2, ss3, ss4, ss5, ss6);

        const float r0 = rcp_hw(ss0);
        const float r1 = rcp_hw(ss1);
        const float r2 = rcp_hw(ss2);
        const float r3 = rcp_hw(ss3);
        const float r4 = rcp_hw(ss4);
        const float r5 = rcp_hw(ss5);
        const float r6 = rcp_hw(ss6);
        U[0] = w0 * r0; U[1] = w1 * r1; U[2] = w2 * r2; U[3] = w3 * r3;
        U[4] = w4 * r4; U[5] = w5 * r5; U[6] = w6 * r6;
    }

    // ---- Epilogue: P = U * bT; normalize by total (+TINY) ----
    float pr[NB];
    float rowsum = 0.f;
    #pragma unroll
    for (int j = 0; j < NB; ++j) {
        pr[j] = U[j] * bT[j];
        rowsum += pr[j];
    }
    const float total = wave_sum_bcast(rowsum);   // ~1 at convergence
    const float inv = 1.0f / (total + TINY_);
    #pragma unroll
    for (int j = 0; j < NB; ++j)
        out[lane * NB + j] = pr[j] * inv;
}

extern "C" void kernel_launch(void* const* d_in, const int* in_sizes, int n_in,
                              void* d_out, int out_size, void* d_ws, size_t ws_size,
                              hipStream_t stream) {
    const float* theta = (const float*)d_in[0];
    const float* phi   = (const float*)d_in[1];
    const float* n     = (const float*)d_in[2];
    const float* sens  = (const float*)d_in[3];
    const float* err   = (const float*)d_in[4];
    float* out = (float*)d_out;

    sinkhorn_kernel<<<1, 64, 0, stream>>>(theta, phi, n, sens, err, out);
}